// Round 6
// baseline (2549.476 us; speedup 1.0000x reference)
//
#include <hip/hip_runtime.h>
#include <stdint.h>

// ---------------------------------------------------------------------------
// BesselConv2d on MI355X (gfx950)
//
// k1: pad+convert x (fp32 NCHW) -> xp bf16 NHWC, zero-padded to 72x72.
// k2: build Wfb[tap][ch'][cin] bf16, ch' = cout*32 + (part*16+m).
// k3: implicit-GEMM conv, fused square/group-reduce/bias epilogue.
//
// R12 = R11 (A 5-row ring + uniform slot counters + XCD remap; 1954us,
// MfmaUtil 70.6, 0 conflicts, no spill) + B moved LDS -> registers:
//   - LDS was the binding pipe (226KB/slot ~ 61 B/cyc vs ~61-85 eff
//     ceiling; MfmaUtil == demand ratio). 96KB read/block-tap is
//     invariant across 4-wave tilings -> only fix is B out of LDS.
//   - per-lane direct global loads fetch the IDENTICAL fragment bytes the
//     swizzled-LDS path delivered (row ct*128+wcol*64+j*16+lr, cin chunk
//     (kk*4+quad)*8). Wfb ct-slice (1.3MB) is L2-resident via XCD remap
//     (R7's FETCH blowup was pre-remap).
//   - anti-spill: constant-indexed arrays only (no pointer-passed lambda,
//     R7's SROA killer) + amdgpu_waves_per_eu(2,2) pins 256-VGPR budget
//     (live ~217: acc 128 + B 32 + A 32 + addr).
//   - half-tap software pipeline: B(t,kk1) issued before kk0 MFMAs,
//     B(t+1,kk0) before kk1 MFMAs; 2 fragment sets live.
//   - Bs gone: LDS 77->45KB; barrier per dy (81 -> 9), waves free-run
//     across 9 taps (phase decorrelation).
// R8's 32x32 MFMA stays reverted (unmodeled +4cyc/ds_read conflicts).
// ---------------------------------------------------------------------------

typedef unsigned short ushort_t;
typedef __attribute__((ext_vector_type(8))) short short8;   // 8 bf16 = 4 VGPRs
typedef __attribute__((ext_vector_type(4))) float float4v;  // 4 fp32 acc

typedef const void __attribute__((address_space(1)))* gptr_t;
typedef void __attribute__((address_space(3)))* sptr_t;

__device__ __forceinline__ ushort_t f2bf(float f) {
    union { float f; uint32_t u; } v; v.f = f;
    uint32_t u = v.u;
    u += 0x7fffu + ((u >> 16) & 1u);   // round-to-nearest-even
    return (ushort_t)(u >> 16);
}

// ---------------------------------------------------------------------------
// Kernel 1: x[32][64][64][64] (NCHW fp32) -> xp[32][72][72][64] (NHWC bf16)
// ---------------------------------------------------------------------------
__global__ __launch_bounds__(256) void pad_kernel(const float* __restrict__ x,
                                                  ushort_t* __restrict__ xp) {
    __shared__ float lds[64 * 65];
    const int hp  = blockIdx.x;   // 0..71
    const int b   = blockIdx.y;   // 0..31
    const int tid = threadIdx.x;
    const int h   = hp - 4;
    const bool hvalid = (h >= 0 && h < 64);
    if (hvalid) {
        #pragma unroll
        for (int it = 0; it < 16; ++it) {
            int idx = it * 256 + tid;
            int cin = idx >> 6, w = idx & 63;
            lds[w * 65 + cin] = x[((b * 64 + cin) * 64 + h) * 64 + w];
        }
    }
    __syncthreads();
    #pragma unroll
    for (int it = 0; it < 18; ++it) {
        int o = it * 256 + tid;
        int wp = o >> 6, cin = o & 63;
        int w = wp - 4;
        float val = (hvalid && w >= 0 && w < 64) ? lds[w * 65 + cin] : 0.0f;
        xp[((b * 72 + hp) * 72 + wp) * 64 + cin] = f2bf(val);
    }
}

// ---------------------------------------------------------------------------
// Kernel 2: Wfb[t][ch'][cin] bf16, ch' = cout*32 + g, g = part*16 + m.
// ---------------------------------------------------------------------------
__global__ __launch_bounds__(256) void wf_kernel(const float* __restrict__ Tr,
                                                 const float* __restrict__ Ti,
                                                 const float* __restrict__ wr,
                                                 const float* __restrict__ wi,
                                                 ushort_t* __restrict__ Wfb) {
    __shared__ float lds[64 * 65];
    const int g   = blockIdx.x;        // 0..31
    const int t   = blockIdx.y;        // 0..80
    const int part = g >> 4, m = g & 15;
    const int tid = threadIdx.x;
    #pragma unroll
    for (int it = 0; it < 16; ++it) {
        int cc = it * 256 + tid;       // cin*64 + cout
        float acc = 0.f;
        #pragma unroll
        for (int j = 0; j < 8; ++j) {
            float tr  = Tr[(m * 81 + t) * 8 + j];
            float ti  = Ti[(m * 81 + t) * 8 + j];
            float wrv = wr[(m * 8 + j) * 4096 + cc];
            float wiv = wi[(m * 8 + j) * 4096 + cc];
            acc += (part == 0) ? (tr * wrv - ti * wiv) : (tr * wiv + ti * wrv);
        }
        lds[(cc & 63) * 65 + (cc >> 6)] = acc;
    }
    __syncthreads();
    #pragma unroll
    for (int it = 0; it < 16; ++it) {
        int o = it * 256 + tid;        // cout*64 + cin
        int cout = o >> 6, cin = o & 63;
        Wfb[(t * 2048 + cout * 32 + g) * 64 + cin] = f2bf(lds[cout * 65 + cin]);
    }
}

// ---------------------------------------------------------------------------
// Kernel 3: implicit-GEMM conv.
// Block: 256 px (4 output rows) x 128 ch. Wave: 128 px x 64 ch.
// As: 5-row ring [5][72][64] (XOR-16B-seg swizzled, key = px&7); stage the
//     single new row at the top of each dy (slot via uniform counters).
// B:  per-lane global->VGPR fragments (L2-resident via XCD remap),
//     half-tap software pipeline, 2 named sets (bc = kk0, bn = kk1).
// Barrier: one per dy (9 total). Grid: 1-D 8192, XCD-chunked remap.
// ---------------------------------------------------------------------------
__global__ __launch_bounds__(256, 2) __attribute__((amdgpu_waves_per_eu(2, 2)))
void conv_kernel(const ushort_t* __restrict__ xp,
                 const ushort_t* __restrict__ Wfb,
                 const float* __restrict__ bias,
                 float* __restrict__ out) {
    __shared__ alignas(16) ushort_t As[5 * 72 * 64];       // 45 KB ring only

    const int bid = blockIdx.x;                      // 0..8191
    const int L   = (bid & 7) * 1024 + (bid >> 3);   // XCD-chunked, bijective
    const int ct  = L >> 9;                          // 0..15
    const int pt  = L & 511;                         // 0..511
    const int b    = pt >> 4;
    const int h0   = (pt & 15) * 4;     // output rows h0..h0+3
    const int tid  = threadIdx.x;
    const int wv   = tid >> 6;
    const int lane = tid & 63;
    const int wrow = wv >> 1, wcol = wv & 1;   // px half (2 rows) / ch half
    const int quad = lane >> 4, lr = lane & 15;
    const int lsw  = ((lane & ~7) | ((lane ^ (lane >> 3)) & 7)) * 16;

    float4v acc[8][4];
    #pragma unroll
    for (int i = 0; i < 8; ++i)
        #pragma unroll
        for (int j = 0; j < 4; ++j) {
            float4v z = {0.f, 0.f, 0.f, 0.f};
            acc[i][j] = z;
        }

    const char* xpb = (const char*)xp;
    // Per-lane B fragment base: row = ct*128 + wcol*64 + j*16 + lr (stride
    // 128B), cin chunk (kk*4+quad)*8 elems -> + j*2048 + kk*64 + quad*16.
    const char* tb = (const char*)Wfb
        + (size_t)(ct * 128 + wcol * 64 + lr) * 128 + (size_t)quad * 16;

    // Stage one padded row (h0-relative row, ring slot). Both args are
    // wave-uniform runtime ints; 9 chunks of 1 KB over 4 waves.
    auto stageA = [&](int row, int slot) {
        char* dstb = (char*)As + slot * 9216;
        const char* gb = xpb + (size_t)(b * 72 + h0 + row) * 9216 + (size_t)lsw;
        __builtin_amdgcn_global_load_lds((gptr_t)(gb + (size_t)wv * 1024),
            (sptr_t)(dstb + wv * 1024), 16, 0, 0);
        __builtin_amdgcn_global_load_lds((gptr_t)(gb + (size_t)(wv + 4) * 1024),
            (sptr_t)(dstb + (wv + 4) * 1024), 16, 0, 0);
        if (wv == 0)
            __builtin_amdgcn_global_load_lds((gptr_t)(gb + (size_t)8 * 1024),
                (sptr_t)(dstb + 8 * 1024), 16, 0, 0);
    };

    stageA(0, 0); stageA(1, 1); stageA(2, 2); stageA(3, 3);

    // Prologue: B(t=0, kk=0) fragments.
    short8 bc[4], bn[4];
    bc[0] = *(const short8*)(tb);
    bc[1] = *(const short8*)(tb + 2048);
    bc[2] = *(const short8*)(tb + 4096);
    bc[3] = *(const short8*)(tb + 6144);

    // Wave-uniform ring-slot counters (conditional ++ per dy, no modulo).
    const int wrowu = __builtin_amdgcn_readfirstlane(wrow);
    int s4  = 4;               // slot of row dy+4 (staged at dy top)
    int rs0 = wrowu * 2;       // slot of this wave's first A row
    int rs1 = rs0 + 1;         // slot of second A row

    for (int dy = 0; dy < 9; ++dy) {
        __syncthreads();                 // rows dy..dy+3 staged & visible
        if (dy < 8) stageA(dy + 4, s4);  // 4-dy deadline, drained next barrier
        const int ab0 = rs0 * 72;        // wave-uniform row bases
        const int ab1 = rs1 * 72;
        for (int dx = 0; dx < 9; ++dx) {
            const int t = dy * 9 + dx;
            const int akey = (lr + dx) & 7;
            const int pxb  = lr + dx;

            // issue B(t, kk1) -> bn (consumed after kk0's MFMAs)
            bn[0] = *(const short8*)(tb + 64);
            bn[1] = *(const short8*)(tb + 2048 + 64);
            bn[2] = *(const short8*)(tb + 4096 + 64);
            bn[3] = *(const short8*)(tb + 6144 + 64);

            // ---- kk = 0: A frags + MFMA with bc ----
            {
                const int aslot = (quad ^ akey) * 8;
                short8 a[8];
                #pragma unroll
                for (int i = 0; i < 8; ++i) {
                    const int ab = (i >> 2) ? ab1 : ab0;
                    a[i] = *(const short8*)&As[(ab + pxb + (i & 3) * 16) * 64 + aslot];
                }
                #pragma unroll
                for (int i = 0; i < 8; ++i)
                    #pragma unroll
                    for (int j = 0; j < 4; ++j)
                        acc[i][j] = __builtin_amdgcn_mfma_f32_16x16x32_bf16(
                            a[i], bc[j], acc[i][j], 0, 0, 0);
            }

            // issue B(t+1, kk0) -> bc (clamped at t=80; data unused)
            {
                const char* tbn = tb + (t < 80 ? 262144 : 0);
                bc[0] = *(const short8*)(tbn);
                bc[1] = *(const short8*)(tbn + 2048);
                bc[2] = *(const short8*)(tbn + 4096);
                bc[3] = *(const short8*)(tbn + 6144);
            }

            // ---- kk = 1: A frags + MFMA with bn ----
            {
                const int aslot = ((4 + quad) ^ akey) * 8;
                short8 a[8];
                #pragma unroll
                for (int i = 0; i < 8; ++i) {
                    const int ab = (i >> 2) ? ab1 : ab0;
                    a[i] = *(const short8*)&As[(ab + pxb + (i & 3) * 16) * 64 + aslot];
                }
                #pragma unroll
                for (int i = 0; i < 8; ++i)
                    #pragma unroll
                    for (int j = 0; j < 4; ++j)
                        acc[i][j] = __builtin_amdgcn_mfma_f32_16x16x32_bf16(
                            a[i], bn[j], acc[i][j], 0, 0, 0);
            }

            tb += 262144;                // -> tap t+1
        }
        // advance ring (wave-uniform scalar math)
        s4  = (s4  == 4) ? 0 : s4  + 1;
        rs0 = (rs0 == 4) ? 0 : rs0 + 1;
        rs1 = (rs1 == 4) ? 0 : rs1 + 1;
    }

    // Epilogue: wave's 64 ch = 2 couts x 32 groups; 128 px = 2 output rows.
    const int c0 = ct * 4 + wcol * 2;
    const float b0 = bias[c0], b1 = bias[c0 + 1];
    #pragma unroll
    for (int i = 0; i < 8; ++i) {
        #pragma unroll
        for (int reg = 0; reg < 4; ++reg) {
            float v0 = acc[i][0][reg] * acc[i][0][reg] + acc[i][1][reg] * acc[i][1][reg];
            float v1 = acc[i][2][reg] * acc[i][2][reg] + acc[i][3][reg] * acc[i][3][reg];
            #pragma unroll
            for (int off = 1; off <= 8; off <<= 1) {
                v0 += __shfl_xor(v0, off, 64);
                v1 += __shfl_xor(v1, off, 64);
            }
            if (lr == 0) {
                const int w = (i & 3) * 16 + quad * 4 + reg;
                const int h = h0 + wrow * 2 + (i >> 2);
                out[((b * 64 + c0    ) * 64 + h) * 64 + w] = v0 + b0;
                out[((b * 64 + c0 + 1) * 64 + h) * 64 + w] = v1 + b1;
            }
        }
    }
}

// ---------------------------------------------------------------------------
extern "C" void kernel_launch(void* const* d_in, const int* in_sizes, int n_in,
                              void* d_out, int out_size, void* d_ws, size_t ws_size,
                              hipStream_t stream) {
    const float* x    = (const float*)d_in[0];
    const float* Tr   = (const float*)d_in[1];
    const float* Ti   = (const float*)d_in[2];
    const float* wr   = (const float*)d_in[3];
    const float* wi   = (const float*)d_in[4];
    const float* bias = (const float*)d_in[5];
    float* out = (float*)d_out;

    ushort_t* xp  = (ushort_t*)d_ws;                          // 21,233,664 B
    ushort_t* Wfb = (ushort_t*)((char*)d_ws + 21233664);      // 21,233,664 B

    pad_kernel<<<dim3(72, 32), 256, 0, stream>>>(x, xp);
    wf_kernel<<<dim3(32, 81), 256, 0, stream>>>(Tr, Ti, wr, wi, Wfb);
    conv_kernel<<<dim3(8192), 256, 0, stream>>>(xp, Wfb, bias, out);
}

// Round 7
// 1934.044 us; speedup vs baseline: 1.3182x; 1.3182x over previous
//
#include <hip/hip_runtime.h>
#include <stdint.h>

// ---------------------------------------------------------------------------
// BesselConv2d on MI355X (gfx950)
//
// k1: pad+convert x (fp32 NCHW) -> xp bf16 NHWC, zero-padded to 72x72.
// k2: build Wfb[tap][ch'][cin] bf16, ch' = cout*32 + (part*16+m).
// k3: implicit-GEMM conv, fused square/group-reduce/bias epilogue.
//
// R13 = R11 exact revert (A 5-row ring + uniform slot counters + XCD
// remap + Bs LDS dbuf + per-tap barrier; verified 1954us, MfmaUtil 70.6,
// 0 conflicts, no spill) + s_setprio(1/0) around each MFMA cluster (T5:
// helps when CU-level wave phase diversity exists -- our 2 resident
// blocks barrier independently, phase-shifted).
// R12's B-in-VGPR reverted (3rd distinct failure): stride-128B per-lane
// gather saturates L1/TA line-request tracking (~1024 lines/tap/CU) ->
// +1650cyc/tap dead time; FETCH/WRITE clean so not spill/L2. B must stay
// on the contiguous global_load_lds DMA path.
// R8's 32x32 MFMA stays reverted (unmodeled +4cyc/ds_read conflicts).
// Accumulator (128 regs) pins 2 waves/SIMD in the unified file; occupancy
// is not a recoverable axis at this tile size.
// ---------------------------------------------------------------------------

typedef unsigned short ushort_t;
typedef __attribute__((ext_vector_type(8))) short short8;   // 8 bf16 = 4 VGPRs
typedef __attribute__((ext_vector_type(4))) float float4v;  // 4 fp32 acc

typedef const void __attribute__((address_space(1)))* gptr_t;
typedef void __attribute__((address_space(3)))* sptr_t;

__device__ __forceinline__ ushort_t f2bf(float f) {
    union { float f; uint32_t u; } v; v.f = f;
    uint32_t u = v.u;
    u += 0x7fffu + ((u >> 16) & 1u);   // round-to-nearest-even
    return (ushort_t)(u >> 16);
}

// ---------------------------------------------------------------------------
// Kernel 1: x[32][64][64][64] (NCHW fp32) -> xp[32][72][72][64] (NHWC bf16)
// ---------------------------------------------------------------------------
__global__ __launch_bounds__(256) void pad_kernel(const float* __restrict__ x,
                                                  ushort_t* __restrict__ xp) {
    __shared__ float lds[64 * 65];
    const int hp  = blockIdx.x;   // 0..71
    const int b   = blockIdx.y;   // 0..31
    const int tid = threadIdx.x;
    const int h   = hp - 4;
    const bool hvalid = (h >= 0 && h < 64);
    if (hvalid) {
        #pragma unroll
        for (int it = 0; it < 16; ++it) {
            int idx = it * 256 + tid;
            int cin = idx >> 6, w = idx & 63;
            lds[w * 65 + cin] = x[((b * 64 + cin) * 64 + h) * 64 + w];
        }
    }
    __syncthreads();
    #pragma unroll
    for (int it = 0; it < 18; ++it) {
        int o = it * 256 + tid;
        int wp = o >> 6, cin = o & 63;
        int w = wp - 4;
        float val = (hvalid && w >= 0 && w < 64) ? lds[w * 65 + cin] : 0.0f;
        xp[((b * 72 + hp) * 72 + wp) * 64 + cin] = f2bf(val);
    }
}

// ---------------------------------------------------------------------------
// Kernel 2: Wfb[t][ch'][cin] bf16, ch' = cout*32 + g, g = part*16 + m.
// ---------------------------------------------------------------------------
__global__ __launch_bounds__(256) void wf_kernel(const float* __restrict__ Tr,
                                                 const float* __restrict__ Ti,
                                                 const float* __restrict__ wr,
                                                 const float* __restrict__ wi,
                                                 ushort_t* __restrict__ Wfb) {
    __shared__ float lds[64 * 65];
    const int g   = blockIdx.x;        // 0..31
    const int t   = blockIdx.y;        // 0..80
    const int part = g >> 4, m = g & 15;
    const int tid = threadIdx.x;
    #pragma unroll
    for (int it = 0; it < 16; ++it) {
        int cc = it * 256 + tid;       // cin*64 + cout
        float acc = 0.f;
        #pragma unroll
        for (int j = 0; j < 8; ++j) {
            float tr  = Tr[(m * 81 + t) * 8 + j];
            float ti  = Ti[(m * 81 + t) * 8 + j];
            float wrv = wr[(m * 8 + j) * 4096 + cc];
            float wiv = wi[(m * 8 + j) * 4096 + cc];
            acc += (part == 0) ? (tr * wrv - ti * wiv) : (tr * wiv + ti * wrv);
        }
        lds[(cc & 63) * 65 + (cc >> 6)] = acc;
    }
    __syncthreads();
    #pragma unroll
    for (int it = 0; it < 16; ++it) {
        int o = it * 256 + tid;        // cout*64 + cin
        int cout = o >> 6, cin = o & 63;
        Wfb[(t * 2048 + cout * 32 + g) * 64 + cin] = f2bf(lds[cout * 65 + cin]);
    }
}

// ---------------------------------------------------------------------------
// Kernel 3: implicit-GEMM conv.
// Block: 256 px (4 output rows) x 128 ch. Wave: 128 px x 64 ch.
// As: 5-row ring [5][72][64] (XOR-16B-seg swizzled, key = px&7); stage the
//     single new row at dx==0 of each dy (slot via uniform counters).
// Bs: double-buffered per-tap tile [2][128][64] (key = ch&7), prefetched.
// Grid: 1-D 8192, XCD-chunked remap for L2 locality.
// ---------------------------------------------------------------------------
__global__ __launch_bounds__(256, 2) void conv_kernel(const ushort_t* __restrict__ xp,
                                                      const ushort_t* __restrict__ Wfb,
                                                      const float* __restrict__ bias,
                                                      float* __restrict__ out) {
    __shared__ alignas(16) ushort_t As[5 * 72 * 64];       // 45 KB ring
    __shared__ alignas(16) ushort_t Bs[2 * 128 * 64];      // 32 KB (dbuf)

    const int bid = blockIdx.x;                      // 0..8191
    const int L   = (bid & 7) * 1024 + (bid >> 3);   // XCD-chunked, bijective
    const int ct  = L >> 9;                          // 0..15
    const int pt  = L & 511;                         // 0..511
    const int b    = pt >> 4;
    const int h0   = (pt & 15) * 4;     // output rows h0..h0+3
    const int tid  = threadIdx.x;
    const int wv   = tid >> 6;
    const int lane = tid & 63;
    const int wrow = wv >> 1, wcol = wv & 1;   // px half (2 rows) / ch half
    const int quad = lane >> 4, lr = lane & 15;
    const int lsw  = ((lane & ~7) | ((lane ^ (lane >> 3)) & 7)) * 16;

    float4v acc[8][4];
    #pragma unroll
    for (int i = 0; i < 8; ++i)
        #pragma unroll
        for (int j = 0; j < 4; ++j) {
            float4v z = {0.f, 0.f, 0.f, 0.f};
            acc[i][j] = z;
        }

    const char* xpb  = (const char*)xp;
    const char* wfb0 = (const char*)Wfb + (size_t)(ct * 128) * 128;  // +t*262144

    // Stage one padded row (h0-relative row, ring slot). Both args are
    // wave-uniform runtime ints; 9 chunks of 1 KB over 4 waves.
    auto stageA = [&](int row, int slot) {
        char* dstb = (char*)As + slot * 9216;
        const char* gb = xpb + (size_t)(b * 72 + h0 + row) * 9216 + (size_t)lsw;
        __builtin_amdgcn_global_load_lds((gptr_t)(gb + (size_t)wv * 1024),
            (sptr_t)(dstb + wv * 1024), 16, 0, 0);
        __builtin_amdgcn_global_load_lds((gptr_t)(gb + (size_t)(wv + 4) * 1024),
            (sptr_t)(dstb + (wv + 4) * 1024), 16, 0, 0);
        if (wv == 0)
            __builtin_amdgcn_global_load_lds((gptr_t)(gb + (size_t)8 * 1024),
                (sptr_t)(dstb + 8 * 1024), 16, 0, 0);
    };
    auto stageB = [&](int t) {
        const char* base = wfb0 + (size_t)t * 262144;
        char* dst = (char*)Bs + (t & 1) * 16384;
        #pragma unroll
        for (int k2 = 0; k2 < 4; ++k2) {
            const int c2 = wv * 4 + k2;
            __builtin_amdgcn_global_load_lds((gptr_t)(base + (size_t)c2 * 1024 + (size_t)lsw),
                (sptr_t)(dst + c2 * 1024), 16, 0, 0);
        }
    };

    stageA(0, 0); stageA(1, 1); stageA(2, 2); stageA(3, 3);
    stageB(0);

    // Wave-uniform ring-slot counters (conditional ++ per dy, no modulo).
    const int wrowu = __builtin_amdgcn_readfirstlane(wrow);
    int s4  = 4;               // slot of row dy+4 (staged at dx==0)
    int rs0 = wrowu * 2;       // slot of this wave's first A row (dy+wrow*2)
    int rs1 = rs0 + 1;         // slot of second A row

    const int bkey = lr & 7;
    for (int dy = 0; dy < 9; ++dy) {
        const int ab0 = rs0 * 72;   // wave-uniform row bases
        const int ab1 = rs1 * 72;
        for (int dx = 0; dx < 9; ++dx) {
            const int t = dy * 9 + dx;
            __syncthreads();              // staging(t) drained; compute(t-1) done
            if (t < 80) stageB(t + 1);    // prefetch next tap (other buffer)
            if (dx == 0 && dy < 8) stageA(dy + 4, s4);   // 1-tap deadline

            const ushort_t* Bp = Bs + (t & 1) * 8192;
            const int akey = (lr + dx) & 7;
            const int pxb  = lr + dx;
            #pragma unroll
            for (int kk = 0; kk < 2; ++kk) {
                short8 a[8], bb[4];
                const int aslot = ((kk * 4 + quad) ^ akey) * 8;
                const int bslot = ((kk * 4 + quad) ^ bkey) * 8;
                #pragma unroll
                for (int j = 0; j < 4; ++j)
                    bb[j] = *(const short8*)&Bp[(wcol * 64 + j * 16 + lr) * 64 + bslot];
                #pragma unroll
                for (int i = 0; i < 8; ++i) {
                    const int ab = (i >> 2) ? ab1 : ab0;   // compile-time select
                    a[i] = *(const short8*)&As[(ab + pxb + (i & 3) * 16) * 64 + aslot];
                }
                __builtin_amdgcn_s_setprio(1);
                #pragma unroll
                for (int i = 0; i < 8; ++i)
                    #pragma unroll
                    for (int j = 0; j < 4; ++j)
                        acc[i][j] = __builtin_amdgcn_mfma_f32_16x16x32_bf16(
                            a[i], bb[j], acc[i][j], 0, 0, 0);
                __builtin_amdgcn_s_setprio(0);
            }
        }
        // advance ring (wave-uniform scalar math)
        s4  = (s4  == 4) ? 0 : s4  + 1;
        rs0 = (rs0 == 4) ? 0 : rs0 + 1;
        rs1 = (rs1 == 4) ? 0 : rs1 + 1;
    }

    // Epilogue: wave's 64 ch = 2 couts x 32 groups; 128 px = 2 output rows.
    const int c0 = ct * 4 + wcol * 2;
    const float b0 = bias[c0], b1 = bias[c0 + 1];
    #pragma unroll
    for (int i = 0; i < 8; ++i) {
        #pragma unroll
        for (int reg = 0; reg < 4; ++reg) {
            float v0 = acc[i][0][reg] * acc[i][0][reg] + acc[i][1][reg] * acc[i][1][reg];
            float v1 = acc[i][2][reg] * acc[i][2][reg] + acc[i][3][reg] * acc[i][3][reg];
            #pragma unroll
            for (int off = 1; off <= 8; off <<= 1) {
                v0 += __shfl_xor(v0, off, 64);
                v1 += __shfl_xor(v1, off, 64);
            }
            if (lr == 0) {
                const int w = (i & 3) * 16 + quad * 4 + reg;
                const int h = h0 + wrow * 2 + (i >> 2);
                out[((b * 64 + c0    ) * 64 + h) * 64 + w] = v0 + b0;
                out[((b * 64 + c0 + 1) * 64 + h) * 64 + w] = v1 + b1;
            }
        }
    }
}

// ---------------------------------------------------------------------------
extern "C" void kernel_launch(void* const* d_in, const int* in_sizes, int n_in,
                              void* d_out, int out_size, void* d_ws, size_t ws_size,
                              hipStream_t stream) {
    const float* x    = (const float*)d_in[0];
    const float* Tr   = (const float*)d_in[1];
    const float* Ti   = (const float*)d_in[2];
    const float* wr   = (const float*)d_in[3];
    const float* wi   = (const float*)d_in[4];
    const float* bias = (const float*)d_in[5];
    float* out = (float*)d_out;

    ushort_t* xp  = (ushort_t*)d_ws;                          // 21,233,664 B
    ushort_t* Wfb = (ushort_t*)((char*)d_ws + 21233664);      // 21,233,664 B

    pad_kernel<<<dim3(72, 32), 256, 0, stream>>>(x, xp);
    wf_kernel<<<dim3(32, 81), 256, 0, stream>>>(Tr, Ti, wr, wi, Wfb);
    conv_kernel<<<dim3(8192), 256, 0, stream>>>(xp, Wfb, bias, out);
}

// Round 8
// 1931.500 us; speedup vs baseline: 1.3199x; 1.0013x over previous
//
#include <hip/hip_runtime.h>
#include <stdint.h>

// ---------------------------------------------------------------------------
// BesselConv2d on MI355X (gfx950)
//
// k1: pad+convert x (fp32 NCHW) -> xp bf16 NHWC, zero-padded to 72x72.
// k2: build Wfb[tap][ch'][cin] bf16, ch' = cout*32 + (part*16+m).
// k3: implicit-GEMM conv, fused square/group-reduce/bias epilogue.
//
// R14 = R13 (R11 + s_setprio around MFMA clusters; 1934us) +
// amdgpu_waves_per_eu(2,2): LDS already pins 2 blocks/CU (=2 waves/SIMD),
// so raising the VGPR cap is free occupancy-wise. R13's setprio acted as
// a scheduling fence, stretched live ranges past the allocator's 128-reg
// target, and spilled ~5 dwords/thread (WRITE 32768->73728 KB = 20B/thr).
// This removes the spill while keeping setprio's wave-arbitration gain.
//
// Session ledger (verified mechanisms):
//  - R8  32x32 MFMA: +4cyc/ds_read bank conflict (2.5e8) -> reverted.
//  - R7/R12 B-in-VGPR: per-lane stride-128B gather saturates L1/TA line
//    tracking (~1024 lines/tap/CU) -> +1650cyc/tap; B stays on the
//    contiguous global_load_lds DMA path.
//  - R9 runtime-modulo ring: spilled frags (WRITE 401MB) -> R11's
//    wave-uniform incremental slot counters are the fix.
//  - R10 XCD remap: FETCH 606->288MB (L2-resident cohort), kept.
//  - R11 5-row ring + per-dy barrier: 2060->1954us, kept.
// Balance (corrected units): MFMA 2483cyc/SIMD (65%) vs LDS unit
// ~2700cyc/CU (~72%) in a 3810cyc window; effective 1.50PF = 96% of the
// best plain-HIP 8-phase GEMM rate (m201). Residual is phase overlap.
// ---------------------------------------------------------------------------

typedef unsigned short ushort_t;
typedef __attribute__((ext_vector_type(8))) short short8;   // 8 bf16 = 4 VGPRs
typedef __attribute__((ext_vector_type(4))) float float4v;  // 4 fp32 acc

typedef const void __attribute__((address_space(1)))* gptr_t;
typedef void __attribute__((address_space(3)))* sptr_t;

__device__ __forceinline__ ushort_t f2bf(float f) {
    union { float f; uint32_t u; } v; v.f = f;
    uint32_t u = v.u;
    u += 0x7fffu + ((u >> 16) & 1u);   // round-to-nearest-even
    return (ushort_t)(u >> 16);
}

// ---------------------------------------------------------------------------
// Kernel 1: x[32][64][64][64] (NCHW fp32) -> xp[32][72][72][64] (NHWC bf16)
// ---------------------------------------------------------------------------
__global__ __launch_bounds__(256) void pad_kernel(const float* __restrict__ x,
                                                  ushort_t* __restrict__ xp) {
    __shared__ float lds[64 * 65];
    const int hp  = blockIdx.x;   // 0..71
    const int b   = blockIdx.y;   // 0..31
    const int tid = threadIdx.x;
    const int h   = hp - 4;
    const bool hvalid = (h >= 0 && h < 64);
    if (hvalid) {
        #pragma unroll
        for (int it = 0; it < 16; ++it) {
            int idx = it * 256 + tid;
            int cin = idx >> 6, w = idx & 63;
            lds[w * 65 + cin] = x[((b * 64 + cin) * 64 + h) * 64 + w];
        }
    }
    __syncthreads();
    #pragma unroll
    for (int it = 0; it < 18; ++it) {
        int o = it * 256 + tid;
        int wp = o >> 6, cin = o & 63;
        int w = wp - 4;
        float val = (hvalid && w >= 0 && w < 64) ? lds[w * 65 + cin] : 0.0f;
        xp[((b * 72 + hp) * 72 + wp) * 64 + cin] = f2bf(val);
    }
}

// ---------------------------------------------------------------------------
// Kernel 2: Wfb[t][ch'][cin] bf16, ch' = cout*32 + g, g = part*16 + m.
// ---------------------------------------------------------------------------
__global__ __launch_bounds__(256) void wf_kernel(const float* __restrict__ Tr,
                                                 const float* __restrict__ Ti,
                                                 const float* __restrict__ wr,
                                                 const float* __restrict__ wi,
                                                 ushort_t* __restrict__ Wfb) {
    __shared__ float lds[64 * 65];
    const int g   = blockIdx.x;        // 0..31
    const int t   = blockIdx.y;        // 0..80
    const int part = g >> 4, m = g & 15;
    const int tid = threadIdx.x;
    #pragma unroll
    for (int it = 0; it < 16; ++it) {
        int cc = it * 256 + tid;       // cin*64 + cout
        float acc = 0.f;
        #pragma unroll
        for (int j = 0; j < 8; ++j) {
            float tr  = Tr[(m * 81 + t) * 8 + j];
            float ti  = Ti[(m * 81 + t) * 8 + j];
            float wrv = wr[(m * 8 + j) * 4096 + cc];
            float wiv = wi[(m * 8 + j) * 4096 + cc];
            acc += (part == 0) ? (tr * wrv - ti * wiv) : (tr * wiv + ti * wrv);
        }
        lds[(cc & 63) * 65 + (cc >> 6)] = acc;
    }
    __syncthreads();
    #pragma unroll
    for (int it = 0; it < 16; ++it) {
        int o = it * 256 + tid;        // cout*64 + cin
        int cout = o >> 6, cin = o & 63;
        Wfb[(t * 2048 + cout * 32 + g) * 64 + cin] = f2bf(lds[cout * 65 + cin]);
    }
}

// ---------------------------------------------------------------------------
// Kernel 3: implicit-GEMM conv.
// Block: 256 px (4 output rows) x 128 ch. Wave: 128 px x 64 ch.
// As: 5-row ring [5][72][64] (XOR-16B-seg swizzled, key = px&7); stage the
//     single new row at dx==0 of each dy (slot via uniform counters).
// Bs: double-buffered per-tap tile [2][128][64] (key = ch&7), prefetched.
// Grid: 1-D 8192, XCD-chunked remap for L2 locality.
// ---------------------------------------------------------------------------
__global__ __launch_bounds__(256, 2) __attribute__((amdgpu_waves_per_eu(2, 2)))
void conv_kernel(const ushort_t* __restrict__ xp,
                 const ushort_t* __restrict__ Wfb,
                 const float* __restrict__ bias,
                 float* __restrict__ out) {
    __shared__ alignas(16) ushort_t As[5 * 72 * 64];       // 45 KB ring
    __shared__ alignas(16) ushort_t Bs[2 * 128 * 64];      // 32 KB (dbuf)

    const int bid = blockIdx.x;                      // 0..8191
    const int L   = (bid & 7) * 1024 + (bid >> 3);   // XCD-chunked, bijective
    const int ct  = L >> 9;                          // 0..15
    const int pt  = L & 511;                         // 0..511
    const int b    = pt >> 4;
    const int h0   = (pt & 15) * 4;     // output rows h0..h0+3
    const int tid  = threadIdx.x;
    const int wv   = tid >> 6;
    const int lane = tid & 63;
    const int wrow = wv >> 1, wcol = wv & 1;   // px half (2 rows) / ch half
    const int quad = lane >> 4, lr = lane & 15;
    const int lsw  = ((lane & ~7) | ((lane ^ (lane >> 3)) & 7)) * 16;

    float4v acc[8][4];
    #pragma unroll
    for (int i = 0; i < 8; ++i)
        #pragma unroll
        for (int j = 0; j < 4; ++j) {
            float4v z = {0.f, 0.f, 0.f, 0.f};
            acc[i][j] = z;
        }

    const char* xpb  = (const char*)xp;
    const char* wfb0 = (const char*)Wfb + (size_t)(ct * 128) * 128;  // +t*262144

    // Stage one padded row (h0-relative row, ring slot). Both args are
    // wave-uniform runtime ints; 9 chunks of 1 KB over 4 waves.
    auto stageA = [&](int row, int slot) {
        char* dstb = (char*)As + slot * 9216;
        const char* gb = xpb + (size_t)(b * 72 + h0 + row) * 9216 + (size_t)lsw;
        __builtin_amdgcn_global_load_lds((gptr_t)(gb + (size_t)wv * 1024),
            (sptr_t)(dstb + wv * 1024), 16, 0, 0);
        __builtin_amdgcn_global_load_lds((gptr_t)(gb + (size_t)(wv + 4) * 1024),
            (sptr_t)(dstb + (wv + 4) * 1024), 16, 0, 0);
        if (wv == 0)
            __builtin_amdgcn_global_load_lds((gptr_t)(gb + (size_t)8 * 1024),
                (sptr_t)(dstb + 8 * 1024), 16, 0, 0);
    };
    auto stageB = [&](int t) {
        const char* base = wfb0 + (size_t)t * 262144;
        char* dst = (char*)Bs + (t & 1) * 16384;
        #pragma unroll
        for (int k2 = 0; k2 < 4; ++k2) {
            const int c2 = wv * 4 + k2;
            __builtin_amdgcn_global_load_lds((gptr_t)(base + (size_t)c2 * 1024 + (size_t)lsw),
                (sptr_t)(dst + c2 * 1024), 16, 0, 0);
        }
    };

    stageA(0, 0); stageA(1, 1); stageA(2, 2); stageA(3, 3);
    stageB(0);

    // Wave-uniform ring-slot counters (conditional ++ per dy, no modulo).
    const int wrowu = __builtin_amdgcn_readfirstlane(wrow);
    int s4  = 4;               // slot of row dy+4 (staged at dx==0)
    int rs0 = wrowu * 2;       // slot of this wave's first A row (dy+wrow*2)
    int rs1 = rs0 + 1;         // slot of second A row

    const int bkey = lr & 7;
    for (int dy = 0; dy < 9; ++dy) {
        const int ab0 = rs0 * 72;   // wave-uniform row bases
        const int ab1 = rs1 * 72;
        for (int dx = 0; dx < 9; ++dx) {
            const int t = dy * 9 + dx;
            __syncthreads();              // staging(t) drained; compute(t-1) done
            if (t < 80) stageB(t + 1);    // prefetch next tap (other buffer)
            if (dx == 0 && dy < 8) stageA(dy + 4, s4);   // 1-tap deadline

            const ushort_t* Bp = Bs + (t & 1) * 8192;
            const int akey = (lr + dx) & 7;
            const int pxb  = lr + dx;
            #pragma unroll
            for (int kk = 0; kk < 2; ++kk) {
                short8 a[8], bb[4];
                const int aslot = ((kk * 4 + quad) ^ akey) * 8;
                const int bslot = ((kk * 4 + quad) ^ bkey) * 8;
                #pragma unroll
                for (int j = 0; j < 4; ++j)
                    bb[j] = *(const short8*)&Bp[(wcol * 64 + j * 16 + lr) * 64 + bslot];
                #pragma unroll
                for (int i = 0; i < 8; ++i) {
                    const int ab = (i >> 2) ? ab1 : ab0;   // compile-time select
                    a[i] = *(const short8*)&As[(ab + pxb + (i & 3) * 16) * 64 + aslot];
                }
                __builtin_amdgcn_s_setprio(1);
                #pragma unroll
                for (int i = 0; i < 8; ++i)
                    #pragma unroll
                    for (int j = 0; j < 4; ++j)
                        acc[i][j] = __builtin_amdgcn_mfma_f32_16x16x32_bf16(
                            a[i], bb[j], acc[i][j], 0, 0, 0);
                __builtin_amdgcn_s_setprio(0);
            }
        }
        // advance ring (wave-uniform scalar math)
        s4  = (s4  == 4) ? 0 : s4  + 1;
        rs0 = (rs0 == 4) ? 0 : rs0 + 1;
        rs1 = (rs1 == 4) ? 0 : rs1 + 1;
    }

    // Epilogue: wave's 64 ch = 2 couts x 32 groups; 128 px = 2 output rows.
    const int c0 = ct * 4 + wcol * 2;
    const float b0 = bias[c0], b1 = bias[c0 + 1];
    #pragma unroll
    for (int i = 0; i < 8; ++i) {
        #pragma unroll
        for (int reg = 0; reg < 4; ++reg) {
            float v0 = acc[i][0][reg] * acc[i][0][reg] + acc[i][1][reg] * acc[i][1][reg];
            float v1 = acc[i][2][reg] * acc[i][2][reg] + acc[i][3][reg] * acc[i][3][reg];
            #pragma unroll
            for (int off = 1; off <= 8; off <<= 1) {
                v0 += __shfl_xor(v0, off, 64);
                v1 += __shfl_xor(v1, off, 64);
            }
            if (lr == 0) {
                const int w = (i & 3) * 16 + quad * 4 + reg;
                const int h = h0 + wrow * 2 + (i >> 2);
                out[((b * 64 + c0    ) * 64 + h) * 64 + w] = v0 + b0;
                out[((b * 64 + c0 + 1) * 64 + h) * 64 + w] = v1 + b1;
            }
        }
    }
}

// ---------------------------------------------------------------------------
extern "C" void kernel_launch(void* const* d_in, const int* in_sizes, int n_in,
                              void* d_out, int out_size, void* d_ws, size_t ws_size,
                              hipStream_t stream) {
    const float* x    = (const float*)d_in[0];
    const float* Tr   = (const float*)d_in[1];
    const float* Ti   = (const float*)d_in[2];
    const float* wr   = (const float*)d_in[3];
    const float* wi   = (const float*)d_in[4];
    const float* bias = (const float*)d_in[5];
    float* out = (float*)d_out;

    ushort_t* xp  = (ushort_t*)d_ws;                          // 21,233,664 B
    ushort_t* Wfb = (ushort_t*)((char*)d_ws + 21233664);      // 21,233,664 B

    pad_kernel<<<dim3(72, 32), 256, 0, stream>>>(x, xp);
    wf_kernel<<<dim3(32, 81), 256, 0, stream>>>(Tr, Ti, wr, wi, Wfb);
    conv_kernel<<<dim3(8192), 256, 0, stream>>>(xp, Wfb, bias, out);
}